// Round 2
// baseline (363.309 us; speedup 1.0000x reference)
//
#include <hip/hip_runtime.h>
#include <hip/hip_bf16.h>

typedef unsigned int u32;
typedef unsigned short u16;

#define DEVI __device__ __forceinline__

DEVI float asf(u32 u){ union{u32 i; float f;} v; v.i=u; return v.f; }
DEVI float bflo(u32 u){ return asf(u<<16); }
DEVI float bfhi(u32 u){ return asf(u & 0xffff0000u); }
DEVI u16 f2b(float x){ u32 b = __float_as_uint(x); u32 r = b + 0x7fffu + ((b>>16)&1u); return (u16)(r>>16); }
DEVI float b2f(u16 h){ return asf(((u32)h)<<16); }
DEVI float lk(float x){ return x > 0.f ? x : 0.01f*x; }

DEVI float ld1(const float* p, int i){ return p[i]; }
DEVI float ld1(const u16* p, int i){ return b2f(p[i]); }
DEVI float2 ld2(const float* p, int i){ return *reinterpret_cast<const float2*>(p+i); }
DEVI float2 ld2(const u16* p, int i){ u32 u = *reinterpret_cast<const u32*>(p+i); return make_float2(bflo(u), bfhi(u)); }
DEVI void st1(float* p, int i, float v){ p[i]=v; }
DEVI void st1(u16* p, int i, float v){ p[i]=f2b(v); }

// LDS map (bytes), regions reused by liveness:
//  ST   @0      f32 [32][84]   states (conv32|pos2|onehot32|act16), dead after P3
//  SC   @0      f32 [32][32]   score/weight (P5..P7)
//  SE   @10752  u16 [32][132]  ; alias: A (conv in) @10752, AGG f32[32][128] @10752 (P7+)
//  SA   @19200  u16 [32][132]  ; alias: C1 @20352 (f32 [32][144])
//  SQm  @27648  u16 [32][132]
//  Q    @36096  u16 [32][132]  ; alias: WT/WT4 staging @36096, H1 f32[32][64] @36096 (P8+)
//  K    @44544  u16 [32][132]  ; alias: F1T u16[128][68] @44544 (P8), F2T f32[64][16] @44544 (P9)
//  V    @52992  u16 [32][132]
//  conv weights: CW1 @38784 f32[432], CW2 @40512 f32[32][145]   (conv phase only)
#define SMEM_BYTES 61952

template<typename T>
__global__ __launch_bounds__(512, 4)
void fused_kernel(const T* __restrict__ xs, const T* __restrict__ pos, const T* __restrict__ oh,
                  const T* __restrict__ act,
                  const T* __restrict__ c1w, const T* __restrict__ c1b,
                  const T* __restrict__ c2w, const T* __restrict__ c2b,
                  const T* __restrict__ saw, const T* __restrict__ sab,
                  const T* __restrict__ sw,  const T* __restrict__ sb,
                  const T* __restrict__ kw,  const T* __restrict__ kb,
                  const T* __restrict__ qw,  const T* __restrict__ qb,
                  const T* __restrict__ vw,  const T* __restrict__ vb,
                  const T* __restrict__ sqw, const T* __restrict__ sqb,
                  const T* __restrict__ f1w, const T* __restrict__ f1b,
                  const T* __restrict__ f2w, const T* __restrict__ f2bb,
                  T* __restrict__ outv, T* __restrict__ outw, const int* __restrict__ flag)
{
    if (*flag != (sizeof(T)==2 ? 1 : 0)) return;   // wrong-dtype instantiation: no-op
    __shared__ __align__(16) char smem[SMEM_BYTES];

    const int b = blockIdx.x, tid = threadIdx.x;
    float* STf = (float*)(smem);
    float* Af  = (float*)(smem + 10752);
    float* C1f = (float*)(smem + 20352);
    float* W1f = (float*)(smem + 38784);
    float* W2f = (float*)(smem + 40512);

    // ---------------- P0: stage inputs + conv weights ----------------
    for (int i = tid*2; i < 2400; i += 1024) { float2 v = ld2(xs, b*2400 + i); Af[i]=v.x; Af[i+1]=v.y; }
    for (int i = tid; i < 432; i += 512) W1f[i] = ld1(c1w, i);
    for (int i = tid*2; i < 4608; i += 1024) {
        float2 v = ld2(c2w, i);
        int oc = i/144, r = i - oc*144;
        W2f[oc*145+r] = v.x; W2f[oc*145+r+1] = v.y;
    }
    for (int i = tid; i < 64; i += 512)  { int n=i>>1, j=i&1;  STf[n*84+32+j] = ld1(pos, (b*32+n)*2+j); }
    for (int i = tid; i < 1024; i += 512){ int n=i>>5, m=i&31; STf[n*84+34+m] = ld1(oh, (b*32+n)*32+m); }
    for (int i = tid; i < 512; i += 512) { int n=i>>4, j=i&15; STf[n*84+66+j] = ld1(act, (b*32+n)*16+j); }
    __syncthreads();

    // ---------------- P1: conv1 3->16, 5x5->3x3, leaky ----------------
    for (int o = tid; o < 4608; o += 512) {
        int n = o/144, r = o - n*144, oc = r/9, p = r - oc*9, y = p/3, x = p - y*3;
        const float* ap = Af + n*75;
        const float* wp = W1f + oc*27;
        float acc = ld1(c1b, oc);
        #pragma unroll
        for (int i = 0; i < 3; ++i)
          #pragma unroll
          for (int ky = 0; ky < 3; ++ky)
            #pragma unroll
            for (int kx = 0; kx < 3; ++kx)
              acc += ap[i*25 + (y+ky)*5 + (x+kx)] * wp[i*9+ky*3+kx];
        C1f[n*144 + oc*9 + p] = lk(acc);
    }
    __syncthreads();

    // ---------------- P2: conv2 16->32, 3x3->1x1, leaky -> states[0..31] ----------------
    #pragma unroll
    for (int rep = 0; rep < 2; ++rep) {
        int o = tid + rep*512; int n = o>>5, oc = o&31;
        const float* cp = C1f + n*144; const float* wp = W2f + oc*145;
        float acc = ld1(c2b, oc);
        #pragma unroll 16
        for (int i = 0; i < 144; ++i) acc += cp[i]*wp[i];
        STf[n*84 + oc] = lk(acc);
    }
    __syncthreads();

    // ---------------- P3: se / sa / sq  (states -> 128, leaky) ----------------
    u16* WT = (u16*)(smem + 36096);
    {
        const T* gw[3] = {sw, saw, sqw};
        const T* gb[3] = {sb, sab, sqb};
        const int Ks[3] = {66, 82, 66};
        u16* dst[3] = {(u16*)(smem+10752), (u16*)(smem+19200), (u16*)(smem+27648)};
        #pragma unroll
        for (int li = 0; li < 3; ++li) {
            const int K = Ks[li];
            for (int i = tid*2; i < 128*K; i += 1024) {   // stage W^T (bf16, stride 132)
                float2 v = ld2(gw[li], i);
                int c = i/K, k = i - c*K;
                WT[k*132 + c]     = f2b(v.x);
                WT[(k+1)*132 + c] = f2b(v.y);
            }
            __syncthreads();
            int n = tid>>4, c0 = (tid&15)*8;
            float acc[8];
            #pragma unroll
            for (int j=0;j<8;++j) acc[j] = ld1(gb[li], c0+j);
            const float* sp = STf + n*84;
            #pragma unroll 2
            for (int k = 0; k < K; ++k) {
                float sv = sp[k];
                uint2 wa = *reinterpret_cast<const uint2*>(WT + k*132 + c0);
                uint2 wb = *reinterpret_cast<const uint2*>(WT + k*132 + c0 + 4);
                acc[0] += sv*bflo(wa.x); acc[1] += sv*bfhi(wa.x);
                acc[2] += sv*bflo(wa.y); acc[3] += sv*bfhi(wa.y);
                acc[4] += sv*bflo(wb.x); acc[5] += sv*bfhi(wb.x);
                acc[6] += sv*bflo(wb.y); acc[7] += sv*bfhi(wb.y);
            }
            u16* dp = dst[li] + n*132 + c0;
            #pragma unroll
            for (int j=0;j<8;++j) dp[j] = f2b(lk(acc[j]));
            __syncthreads();
        }
    }

    // ---------------- P4: queries/keys/vals (128->128, no act) ----------------
    u16* SEh = (u16*)(smem+10752);
    u16* SAh = (u16*)(smem+19200);
    u16* Qh  = (u16*)(smem+36096);
    u16* Kh  = (u16*)(smem+44544);
    u16* Vh  = (u16*)(smem+52992);
    u16* WT4 = (u16*)(smem+36096);
    {
        int n = tid>>4, c0 = (tid&15)*8;
        const T* gw[3] = {qw, kw, vw};
        const T* gb[3] = {qb, kb, vb};
        float acc[3][8];
        #pragma unroll
        for (int m=0;m<3;++m)
            #pragma unroll
            for (int j=0;j<8;++j) acc[m][j] = ld1(gb[m], c0+j);
        #pragma unroll
        for (int h=0; h<2; ++h) {
            #pragma unroll
            for (int m=0; m<3; ++m) {
                for (int i = tid*2; i < 8192; i += 1024) {   // stage half of W^T
                    int c = i>>6, kk = i&63;
                    float2 v = ld2(gw[m], c*128 + h*64 + kk);
                    WT4[kk*132 + c]     = f2b(v.x);
                    WT4[(kk+1)*132 + c] = f2b(v.y);
                }
                __syncthreads();
                const u16* srcp = (m==0 ? SEh : SAh) + n*132 + h*64;
                #pragma unroll 8
                for (int kk = 0; kk < 64; kk += 2) {
                    u32 sp2 = *reinterpret_cast<const u32*>(srcp + kk);
                    float s0 = bflo(sp2), s1 = bfhi(sp2);
                    uint2 wa = *reinterpret_cast<const uint2*>(WT4 + kk*132 + c0);
                    uint2 wb = *reinterpret_cast<const uint2*>(WT4 + kk*132 + c0 + 4);
                    uint2 wc = *reinterpret_cast<const uint2*>(WT4 + (kk+1)*132 + c0);
                    uint2 wd = *reinterpret_cast<const uint2*>(WT4 + (kk+1)*132 + c0 + 4);
                    acc[m][0] += s0*bflo(wa.x) + s1*bflo(wc.x);
                    acc[m][1] += s0*bfhi(wa.x) + s1*bfhi(wc.x);
                    acc[m][2] += s0*bflo(wa.y) + s1*bflo(wc.y);
                    acc[m][3] += s0*bfhi(wa.y) + s1*bfhi(wc.y);
                    acc[m][4] += s0*bflo(wb.x) + s1*bflo(wd.x);
                    acc[m][5] += s0*bfhi(wb.x) + s1*bfhi(wd.x);
                    acc[m][6] += s0*bflo(wb.y) + s1*bflo(wd.y);
                    acc[m][7] += s0*bfhi(wb.y) + s1*bfhi(wd.y);
                }
                __syncthreads();
            }
        }
        u16* dsts[3] = {Qh, Kh, Vh};
        #pragma unroll
        for (int m=0;m<3;++m){
            u16* dp = dsts[m] + n*132 + c0;
            #pragma unroll
            for (int j=0;j<8;++j) dp[j] = f2b(acc[m][j]);
        }
    }
    __syncthreads();

    // ---------------- P5: score = Q.K^T / sqrt(128) ----------------
    float* SCf = (float*)(smem);
    #pragma unroll
    for (int rep=0; rep<2; ++rep) {
        int o = tid + rep*512; int n = o>>5, m = o&31;
        const u16* qp = Qh + n*132; const u16* kp = Kh + m*132;
        float acc = 0.f;
        #pragma unroll 8
        for (int k=0;k<128;k+=2) {
            u32 qa = *reinterpret_cast<const u32*>(qp + k);
            u32 ka = *reinterpret_cast<const u32*>(kp + k);
            acc += bflo(qa)*bflo(ka) + bfhi(qa)*bfhi(ka);
        }
        SCf[n*32+m] = acc * 0.08838834764831845f;
    }
    __syncthreads();

    // ---------------- P6: off-diagonal softmax (16 lanes per row) + weight out ----------------
    {
        int n = tid>>4, g = tid&15;
        int m0 = (g < n) ? g : g+1;
        int j1 = g+16;
        bool v1 = j1 < 31;
        int m1 = (j1 < n) ? j1 : j1+1;
        float e0 = SCf[n*32+m0];
        float e1 = v1 ? SCf[n*32+m1] : -1e30f;
        float mx = fmaxf(e0, e1);
        #pragma unroll
        for (int d=8; d; d>>=1) mx = fmaxf(mx, __shfl_xor(mx, d, 16));
        float x0 = __expf(e0-mx);
        float x1 = v1 ? __expf(e1-mx) : 0.f;
        float s = x0+x1;
        #pragma unroll
        for (int d=8; d; d>>=1) s += __shfl_xor(s, d, 16);
        float inv = 1.f/s;
        float w0 = x0*inv, w1 = x1*inv;
        SCf[n*32+g] = w0;                 // in-place (wave-lockstep: reads above precede writes)
        if (v1) SCf[n*32+j1] = w1;
        T* wp = outw + (b*32+n)*31;
        st1(wp, g, w0);
        if (v1) st1(wp, j1, w1);
    }
    __syncthreads();

    // ---------------- P7: agg = sum_j weight * vals[offdiag] ----------------
    float* AGGf = (float*)(smem + 10752);
    {
        int c0 = (tid&63)*2, grp = tid>>6;
        float a0[4], a1[4];
        #pragma unroll
        for (int u=0;u<4;++u){ a0[u]=0.f; a1[u]=0.f; }
        for (int j=0;j<31;++j) {
            #pragma unroll
            for (int u=0;u<4;++u) {
                int n = grp + 8*u;
                int m = (j < n) ? j : j+1;
                float wv = SCf[n*32+j];
                u32 vv = *reinterpret_cast<const u32*>(Vh + m*132 + c0);
                a0[u] += wv*bflo(vv);
                a1[u] += wv*bfhi(vv);
            }
        }
        #pragma unroll
        for (int u=0;u<4;++u){
            int n = grp + 8*u;
            AGGf[n*128+c0]   = a0[u];
            AGGf[n*128+c0+1] = a1[u];
        }
    }
    __syncthreads();

    // ---------------- P8: f1 (256->64, leaky), node=[sq|agg] ----------------
    u16* SQh = (u16*)(smem+27648);
    float* H1f = (float*)(smem+36096);
    u16* F1T = (u16*)(smem+44544);
    {
        int n = tid>>4, c0 = (tid&15)*4;
        float acc[4];
        #pragma unroll
        for (int j=0;j<4;++j) acc[j] = ld1(f1b, c0+j);
        #pragma unroll
        for (int h=0; h<2; ++h) {
            for (int i = tid*2; i < 8192; i += 1024) {  // stage f1_w half, transposed (stride 68)
                int c = i>>7, kk = i&127;
                float2 v = ld2(f1w, c*256 + h*128 + kk);
                F1T[kk*68+c]     = f2b(v.x);
                F1T[(kk+1)*68+c] = f2b(v.y);
            }
            __syncthreads();
            #pragma unroll 4
            for (int kk=0; kk<128; kk+=2) {
                float s0, s1;
                if (h==0) { u32 sp2 = *reinterpret_cast<const u32*>(SQh + n*132 + kk); s0=bflo(sp2); s1=bfhi(sp2); }
                else      { float2 f = *reinterpret_cast<const float2*>(AGGf + n*128 + kk); s0=f.x; s1=f.y; }
                uint2 wa = *reinterpret_cast<const uint2*>(F1T + kk*68 + c0);
                uint2 wb = *reinterpret_cast<const uint2*>(F1T + (kk+1)*68 + c0);
                acc[0] += s0*bflo(wa.x) + s1*bflo(wb.x);
                acc[1] += s0*bfhi(wa.x) + s1*bfhi(wb.x);
                acc[2] += s0*bflo(wa.y) + s1*bflo(wb.y);
                acc[3] += s0*bfhi(wa.y) + s1*bfhi(wb.y);
            }
            __syncthreads();
        }
        float* hp = H1f + n*64 + c0;
        #pragma unroll
        for (int j=0;j<4;++j) hp[j] = lk(acc[j]);
    }
    __syncthreads();

    // ---------------- P9: f2 (64->16) -> value out ----------------
    float* F2T = (float*)(smem+44544);
    for (int i = tid; i < 1024; i += 512) {
        int o = i>>6, k = i&63;
        F2T[k*16+o] = ld1(f2w, i);
    }
    __syncthreads();
    {
        int n = tid>>4, o = tid&15;
        float acc = ld1(f2bb, o);
        const float* hp = H1f + n*64;
        #pragma unroll 8
        for (int k=0;k<64;++k) acc += hp[k]*F2T[k*16+o];
        st1(outv, (b*32+n)*16+o, acc);
    }
}

__global__ void detect_k(const u32* oh, int* flag){
    if (threadIdx.x == 0) *flag = (oh[0] == 0x3F800000u) ? 0 : 1;
}

extern "C" void kernel_launch(void* const* d_in, const int* in_sizes, int n_in,
                              void* d_out, int out_size, void* d_ws, size_t ws_size,
                              hipStream_t stream) {
    const int B = in_sizes[0] / (32*75);
    int* flag = (int*)d_ws;
    detect_k<<<1, 64, 0, stream>>>((const u32*)d_in[2], flag);

    // setup_inputs order: 0 agent_states, 1 positions, 2 one_hot, 3 policies(unused), 4 actions,
    // 5 conv1_w, 6 conv1_b, 7 conv2_w, 8 conv2_b, 9 sa_w, 10 sa_b, 11 s_w, 12 s_b,
    // 13 k_w, 14 k_b, 15 q_w, 16 q_b, 17 v_w, 18 v_b, 19 sq_w, 20 sq_b,
    // 21 f1_w, 22 f1_b, 23 f2_w, 24 f2_b
    #define ARGS(TT) \
      (const TT*)d_in[0],(const TT*)d_in[1],(const TT*)d_in[2],(const TT*)d_in[4], \
      (const TT*)d_in[5],(const TT*)d_in[6],(const TT*)d_in[7],(const TT*)d_in[8], \
      (const TT*)d_in[9],(const TT*)d_in[10],(const TT*)d_in[11],(const TT*)d_in[12], \
      (const TT*)d_in[13],(const TT*)d_in[14],(const TT*)d_in[15],(const TT*)d_in[16], \
      (const TT*)d_in[17],(const TT*)d_in[18],(const TT*)d_in[19],(const TT*)d_in[20], \
      (const TT*)d_in[21],(const TT*)d_in[22],(const TT*)d_in[23],(const TT*)d_in[24], \
      (TT*)d_out, (TT*)d_out + (size_t)B*32*16, flag

    fused_kernel<float><<<B, 512, 0, stream>>>(ARGS(float));
    fused_kernel<u16><<<B, 512, 0, stream>>>(ARGS(u16));
    #undef ARGS
}

// Round 3
// 195.524 us; speedup vs baseline: 1.8581x; 1.8581x over previous
//
#include <hip/hip_runtime.h>
#include <hip/hip_bf16.h>

typedef unsigned int u32;
typedef unsigned short u16;
typedef __attribute__((ext_vector_type(8))) short short8;
typedef __attribute__((ext_vector_type(4))) float f32x4;

#define DEVI __device__ __forceinline__

DEVI float asf(u32 u){ union{u32 i; float f;} v; v.i=u; return v.f; }
DEVI float bflo(u32 u){ return asf(u<<16); }
DEVI float bfhi(u32 u){ return asf(u & 0xffff0000u); }
DEVI u16 f2b(float x){ u32 b = __float_as_uint(x); u32 r = b + 0x7fffu + ((b>>16)&1u); return (u16)(r>>16); }
DEVI float b2f(u16 h){ return asf(((u32)h)<<16); }
DEVI float lk(float x){ return x > 0.f ? x : 0.01f*x; }

DEVI float ld1(const float* p, int i){ return p[i]; }
DEVI float ld1(const u16* p, int i){ return b2f(p[i]); }
DEVI float2 ld2(const float* p, int i){ return *reinterpret_cast<const float2*>(p+i); }
DEVI float2 ld2(const u16* p, int i){ u32 u = *reinterpret_cast<const u32*>(p+i); return make_float2(bflo(u), bfhi(u)); }
DEVI void st1(float* p, int i, float v){ p[i]=v; }
DEVI void st1(u16* p, int i, float v){ p[i]=f2b(v); }
DEVI short8 lds8(const u16* p){ return *reinterpret_cast<const short8*>(p); }

#define MFMA(a,b,c) __builtin_amdgcn_mfma_f32_16x16x32_bf16((a),(b),(c),0,0,0)

// ---- weight fragment regions (u16 elements, base = d_ws + 1024 bytes) ----
// P3: 24nt x 3ks x 64lane x 8  = 36864   (n: 0-7 s_w | 8-15 sa_w | 16-23 sq_w; K 96, zero-padded)
// P4: 24nt x 4ks x 64 x 8      = 49152   (n: 0-7 q_w | 8-15 k_w | 16-23 v_w; K 128)
// P8:  4nt x 8ks x 64 x 8      = 16384   (f1_w; K 256 = [sq|agg])
// P9:  1nt x 2ks x 64 x 8      =  1024   (f2_w; K 64)
#define FRAG_P4_OFF 36864
#define FRAG_P8_OFF 86016
#define FRAG_P9_OFF 102400
#define FRAG_TOTAL  103424

template<typename T>
__global__ void prelude_k(const T* __restrict__ sw, const T* __restrict__ saw, const T* __restrict__ sqw,
                          const T* __restrict__ qw, const T* __restrict__ kw, const T* __restrict__ vw,
                          const T* __restrict__ f1w, const T* __restrict__ f2w,
                          u16* __restrict__ frag, const int* __restrict__ flag)
{
    if (*flag != (sizeof(T)==2 ? 1 : 0)) return;
    int idx = blockIdx.x*256 + threadIdx.x;
    if (idx >= FRAG_TOTAL) return;
    if (idx < FRAG_P4_OFF) {
        int j = idx & 7, lane = (idx>>3)&63, r2 = idx>>9;
        int ks = r2 % 3, nt = r2 / 3;
        int fl = lane&15, kg = lane>>4;
        int k = ks*32 + kg*8 + j;
        float w = 0.f;
        if (nt < 8)       { int c = nt*16+fl;      if (k < 66) w = ld1(sw,  c*66+k); }
        else if (nt < 16) { int c = (nt-8)*16+fl;  if (k < 82) w = ld1(saw, c*82+k); }
        else              { int c = (nt-16)*16+fl; if (k < 66) w = ld1(sqw, c*66+k); }
        frag[idx] = f2b(w);
    } else if (idx < FRAG_P8_OFF) {
        int e = idx - FRAG_P4_OFF;
        int j = e&7, lane = (e>>3)&63, r2 = e>>9;
        int ks = r2 & 3, nt = r2 >> 2;
        int fl = lane&15, kg = lane>>4;
        int k = ks*32 + kg*8 + j;
        float w;
        if (nt < 8)       w = ld1(qw, (nt*16+fl)*128 + k);
        else if (nt < 16) w = ld1(kw, ((nt-8)*16+fl)*128 + k);
        else              w = ld1(vw, ((nt-16)*16+fl)*128 + k);
        frag[idx] = f2b(w);
    } else if (idx < FRAG_P9_OFF) {
        int e = idx - FRAG_P8_OFF;
        int j = e&7, lane = (e>>3)&63, r2 = e>>9;
        int ks = r2&7, nt = r2>>3;
        int k = ks*32 + (lane>>4)*8 + j;
        frag[idx] = f2b(ld1(f1w, (nt*16+(lane&15))*256 + k));
    } else {
        int e = idx - FRAG_P9_OFF;
        int j = e&7, lane = (e>>3)&63, r2 = e>>9;   // r2 = ks in {0,1}
        int k = r2*32 + (lane>>4)*8 + j;
        frag[idx] = f2b(ld1(f2w, (lane&15)*64 + k));
    }
}

// ---- LDS map (bytes); strides are odd multiples of 16B for b128 reads ----
#define L_STH 0       // u16 [32][104]  states: conv32|pos2|oh32|act16|pad  [P0->P3]
#define L_SQH 6656    // u16 [32][136]  sq embedding                       [P3->P8]
#define L_SEH 15360   // u16 [32][136]                                     [P3->P4]
#define L_SAH 24064   // u16 [32][136]                                     [P3->P4]
#define L_QH  32768   // u16 [32][136]  queries (pre-scaled)               [P4->P5]
#define L_KH  41472   // u16 [32][136]  keys                               [P4->P5]
#define L_VT  50176   // u16 [128][40]  values TRANSPOSED [c][m]           [P4->P7]
// aliases (liveness-checked):
#define L_AF  6656    // f32 [32][75]   conv input            [P0->P1] (in SQH/SEH)
#define L_W2F 16256   // f32 [32][145]  conv2 w               [P0->P2] (SEH tail/SAH/QH head)
#define L_W1F 34816   // f32 [432]      conv1 w               [P0->P1] (QH)
#define L_C1F 36544   // f32 [32][144]  conv1 out             [P1->P2] (QH tail/KH/VT head)
#define L_SCF 0       // f32 [32][36]   scores                [P5->P6] (STH dead)
#define L_W32 15360   // u16 [32][40]   softmax w, zero diag  [P6->P7] (SEH dead)
#define L_AGG 32768   // u16 [32][136]  agg                   [P7->P8] (QH dead)
#define L_H1  41472   // u16 [32][72]   f1 out                [P8->P9] (KH dead)
#define SMEM_BYTES 60416

template<typename T>
__global__ __launch_bounds__(256, 2)
void fused_kernel(const T* __restrict__ xs, const T* __restrict__ pos, const T* __restrict__ oh,
                  const T* __restrict__ act,
                  const T* __restrict__ c1w, const T* __restrict__ c1b,
                  const T* __restrict__ c2w, const T* __restrict__ c2b,
                  const T* __restrict__ sb,  const T* __restrict__ sab, const T* __restrict__ sqb,
                  const T* __restrict__ qb,  const T* __restrict__ kb,  const T* __restrict__ vb,
                  const T* __restrict__ f1b, const T* __restrict__ f2b_,
                  T* __restrict__ outv, T* __restrict__ outw,
                  const int* __restrict__ flag, const u16* __restrict__ frag)
{
    if (*flag != (sizeof(T)==2 ? 1 : 0)) return;
    __shared__ __align__(16) char smem[SMEM_BYTES];

    const int b = blockIdx.x, tid = threadIdx.x;
    const int lane = tid & 63, wv = tid >> 6;
    const int fl = lane & 15, kg = lane >> 4;

    u16* STh = (u16*)(smem + L_STH);
    u16* SQh = (u16*)(smem + L_SQH);
    u16* SEh = (u16*)(smem + L_SEH);
    u16* SAh = (u16*)(smem + L_SAH);
    u16* Qh  = (u16*)(smem + L_QH);
    u16* Kh  = (u16*)(smem + L_KH);
    u16* Vt  = (u16*)(smem + L_VT);
    float* Af  = (float*)(smem + L_AF);
    float* W1f = (float*)(smem + L_W1F);
    float* W2f = (float*)(smem + L_W2F);
    float* C1f = (float*)(smem + L_C1F);
    float* SCf = (float*)(smem + L_SCF);
    u16* W32h = (u16*)(smem + L_W32);
    u16* AGGh = (u16*)(smem + L_AGG);
    u16* H1h  = (u16*)(smem + L_H1);
    const u16* F3 = frag;
    const u16* F4 = frag + FRAG_P4_OFF;
    const u16* F8 = frag + FRAG_P8_OFF;
    const u16* F9 = frag + FRAG_P9_OFF;

    // ---------------- P0: stage conv input + conv weights + pose/onehot/actions ----------------
    for (int i = tid*2; i < 2400; i += 512) { float2 v = ld2(xs, b*2400 + i); Af[i]=v.x; Af[i+1]=v.y; }
    for (int i = tid; i < 432; i += 256) W1f[i] = ld1(c1w, i);
    for (int i = tid*2; i < 4608; i += 512) {
        float2 v = ld2(c2w, i);
        int oc = i/144, r = i - oc*144;
        W2f[oc*145+r] = v.x; W2f[oc*145+r+1] = v.y;
    }
    for (int i = tid; i < 64; i += 256)   { int n=i>>1, j=i&1;  STh[n*104+32+j] = f2b(ld1(pos,(b*32+n)*2+j)); }
    for (int i = tid; i < 1024; i += 256) { int n=i>>5, m=i&31; STh[n*104+34+m] = f2b(ld1(oh,(b*32+n)*32+m)); }
    for (int i = tid; i < 512; i += 256)  { int n=i>>4, j=i&15; STh[n*104+66+j] = f2b(ld1(act,(b*32+n)*16+j)); }
    for (int i = tid; i < 704; i += 256)  { int n=i/22, j=i-n*22; STh[n*104+82+j] = 0; }  // zero K-pad
    __syncthreads();

    // ---------------- P1: conv1 3->16, 5x5->3x3, leaky (f32 VALU) ----------------
    for (int o = tid; o < 4608; o += 256) {
        int n = o/144, r = o - n*144, oc = r/9, p = r - oc*9, y = p/3, x = p - y*3;
        const float* ap = Af + n*75;
        const float* wp = W1f + oc*27;
        float acc = ld1(c1b, oc);
        #pragma unroll
        for (int i = 0; i < 3; ++i)
          #pragma unroll
          for (int ky = 0; ky < 3; ++ky)
            #pragma unroll
            for (int kx = 0; kx < 3; ++kx)
              acc += ap[i*25 + (y+ky)*5 + (x+kx)] * wp[i*9+ky*3+kx];
        C1f[n*144 + oc*9 + p] = lk(acc);
    }
    __syncthreads();

    // ---------------- P2: conv2 16->32 -> states cols 0..31 (bf16) ----------------
    for (int o = tid; o < 1024; o += 256) {
        int n = o>>5, oc = o&31;
        const float* cp = C1f + n*144; const float* wp = W2f + oc*145;
        float acc = ld1(c2b, oc);
        #pragma unroll 16
        for (int i = 0; i < 144; ++i) acc += cp[i]*wp[i];
        STh[n*104 + oc] = f2b(lk(acc));
    }
    __syncthreads();

    // ---------------- P3: [32x96]@[96x384] -> SE|SA|SQ (MFMA, bias+leaky) ----------------
    for (int t = wv; t < 48; t += 4) {
        int nt = t >> 1, mt = t & 1;
        f32x4 acc = {0.f,0.f,0.f,0.f};
        const u16* ap = STh + (mt*16 + fl)*104 + kg*8;
        const u16* bp = F3 + ((nt*3)*64 + lane)*8;
        #pragma unroll
        for (int ks = 0; ks < 3; ++ks)
            acc = MFMA(lds8(ap + ks*32), lds8(bp + ks*512), acc);
        u16* dst; const T* bias; int colOff;
        if (nt < 8)       { dst = SEh; bias = sb;  colOff = nt*16; }
        else if (nt < 16) { dst = SAh; bias = sab; colOff = (nt-8)*16; }
        else              { dst = SQh; bias = sqb; colOff = (nt-16)*16; }
        float bv = ld1(bias, colOff + fl);
        int rowb = mt*16 + kg*4;
        #pragma unroll
        for (int r = 0; r < 4; ++r)
            dst[(rowb+r)*136 + colOff + fl] = f2b(lk(acc[r] + bv));
    }
    __syncthreads();

    // ---------------- P4: Q|K|V (MFMA; Q pre-scaled by 1/sqrt(128); V transposed) ----------------
    for (int t = wv; t < 48; t += 4) {
        int nt = t >> 1, mt = t & 1;
        const u16* A = (nt < 8) ? SEh : SAh;
        f32x4 acc = {0.f,0.f,0.f,0.f};
        const u16* ap = A + (mt*16 + fl)*136 + kg*8;
        const u16* bp = F4 + ((nt*4)*64 + lane)*8;
        #pragma unroll
        for (int ks = 0; ks < 4; ++ks)
            acc = MFMA(lds8(ap + ks*32), lds8(bp + ks*512), acc);
        int rowb = mt*16 + kg*4;
        if (nt < 8) {
            float bv = ld1(qb, nt*16 + fl);
            #pragma unroll
            for (int r = 0; r < 4; ++r)
                Qh[(rowb+r)*136 + nt*16 + fl] = f2b((acc[r] + bv)*0.08838834764831845f);
        } else if (nt < 16) {
            float bv = ld1(kb, (nt-8)*16 + fl);
            #pragma unroll
            for (int r = 0; r < 4; ++r)
                Kh[(rowb+r)*136 + (nt-8)*16 + fl] = f2b(acc[r] + bv);
        } else {
            int c = (nt-16)*16 + fl;
            float bv = ld1(vb, c);
            #pragma unroll
            for (int r = 0; r < 4; ++r)
                Vt[c*40 + rowb + r] = f2b(acc[r] + bv);
        }
    }
    __syncthreads();

    // ---------------- P5: score = Q @ K^T (both operands from LDS) ----------------
    if (wv < 4) {
        int nt = wv >> 1, mt = wv & 1;
        f32x4 acc = {0.f,0.f,0.f,0.f};
        const u16* ap = Qh + (mt*16 + fl)*136 + kg*8;
        const u16* bp = Kh + (nt*16 + fl)*136 + kg*8;
        #pragma unroll
        for (int ks = 0; ks < 4; ++ks)
            acc = MFMA(lds8(ap + ks*32), lds8(bp + ks*32), acc);
        int rowb = mt*16 + kg*4;
        #pragma unroll
        for (int r = 0; r < 4; ++r)
            SCf[(rowb+r)*36 + nt*16 + fl] = acc[r];
    }
    __syncthreads();

    // ---------------- P6: off-diagonal softmax -> outw + W32 (zero diag) ----------------
    #pragma unroll
    for (int rep = 0; rep < 2; ++rep) {
        int n = (tid>>4) + rep*16, g = tid & 15;
        int m0 = (g < n) ? g : g+1;
        int j1 = g + 16;
        bool v1 = j1 < 31;
        int m1 = (j1 < n) ? j1 : j1+1;
        float e0 = SCf[n*36 + m0];
        float e1 = v1 ? SCf[n*36 + m1] : -1e30f;
        float mx = fmaxf(e0, e1);
        #pragma unroll
        for (int d = 8; d; d >>= 1) mx = fmaxf(mx, __shfl_xor(mx, d, 16));
        float x0 = __expf(e0 - mx);
        float x1 = v1 ? __expf(e1 - mx) : 0.f;
        float s = x0 + x1;
        #pragma unroll
        for (int d = 8; d; d >>= 1) s += __shfl_xor(s, d, 16);
        float inv = 1.f/s;
        float w0 = x0*inv, w1 = x1*inv;
        W32h[n*40 + m0] = f2b(w0);
        if (v1) W32h[n*40 + m1] = f2b(w1);
        if (g == 0) W32h[n*40 + n] = 0;   // +0.0 bf16
        T* wp = outw + (b*32 + n)*31;
        st1(wp, g, w0);
        if (v1) st1(wp, j1, w1);
    }
    __syncthreads();

    // ---------------- P7: agg = W32 @ V  ([32x32]@[32x128], B from Vt) ----------------
    for (int t = wv; t < 16; t += 4) {
        int nt = t >> 1, mt = t & 1;
        const u16* ap = W32h + (mt*16 + fl)*40 + kg*8;
        const u16* bp = Vt + (nt*16 + fl)*40 + kg*8;
        f32x4 acc = {0.f,0.f,0.f,0.f};
        acc = MFMA(lds8(ap), lds8(bp), acc);
        int rowb = mt*16 + kg*4;
        #pragma unroll
        for (int r = 0; r < 4; ++r)
            AGGh[(rowb+r)*136 + nt*16 + fl] = f2b(acc[r]);
    }
    __syncthreads();

    // ---------------- P8: f1 ([32x256]@[256x64], K split sq|agg, bias+leaky) ----------------
    for (int t = wv; t < 8; t += 4) {
        int nt = t >> 1, mt = t & 1;
        f32x4 acc = {0.f,0.f,0.f,0.f};
        const u16* bp = F8 + ((nt*8)*64 + lane)*8;
        #pragma unroll
        for (int ks = 0; ks < 8; ++ks) {
            const u16* ap = ((ks < 4) ? SQh : AGGh) + (mt*16 + fl)*136 + (ks&3)*32 + kg*8;
            acc = MFMA(lds8(ap), lds8(bp + ks*512), acc);
        }
        float bv = ld1(f1b, nt*16 + fl);
        int rowb = mt*16 + kg*4;
        #pragma unroll
        for (int r = 0; r < 4; ++r)
            H1h[(rowb+r)*72 + nt*16 + fl] = f2b(lk(acc[r] + bv));
    }
    __syncthreads();

    // ---------------- P9: f2 ([32x64]@[64x16]) -> value out ----------------
    if (wv < 2) {
        int mt = wv;
        f32x4 acc = {0.f,0.f,0.f,0.f};
        const u16* ap = H1h + (mt*16 + fl)*72 + kg*8;
        const u16* bp = F9 + lane*8;
        #pragma unroll
        for (int ks = 0; ks < 2; ++ks)
            acc = MFMA(lds8(ap + ks*32), lds8(bp + ks*512), acc);
        float bv = ld1(f2b_, fl);
        int rowb = mt*16 + kg*4;
        #pragma unroll
        for (int r = 0; r < 4; ++r)
            st1(outv, (b*32 + rowb + r)*16 + fl, acc[r] + bv);
    }
}

__global__ void detect_k(const u32* oh, int* flag){
    if (threadIdx.x == 0) *flag = (oh[0] == 0x3F800000u) ? 0 : 1;
}

extern "C" void kernel_launch(void* const* d_in, const int* in_sizes, int n_in,
                              void* d_out, int out_size, void* d_ws, size_t ws_size,
                              hipStream_t stream) {
    const int B = in_sizes[0] / (32*75);
    int* flag = (int*)d_ws;
    u16* frag = (u16*)((char*)d_ws + 1024);
    detect_k<<<1, 64, 0, stream>>>((const u32*)d_in[2], flag);

    // indices: 0 xs,1 pos,2 oh,3 policies,4 act, 5 c1w,6 c1b,7 c2w,8 c2b,
    // 9 sa_w,10 sa_b,11 s_w,12 s_b, 13 k_w,14 k_b, 15 q_w,16 q_b, 17 v_w,18 v_b,
    // 19 sq_w,20 sq_b, 21 f1_w,22 f1_b, 23 f2_w,24 f2_b
    const int PRE_GRID = (FRAG_TOTAL + 255)/256;
    #define PARGS(TT) \
      (const TT*)d_in[11],(const TT*)d_in[9],(const TT*)d_in[19], \
      (const TT*)d_in[15],(const TT*)d_in[13],(const TT*)d_in[17], \
      (const TT*)d_in[21],(const TT*)d_in[23], frag, flag
    prelude_k<float><<<PRE_GRID, 256, 0, stream>>>(PARGS(float));
    prelude_k<u16><<<PRE_GRID, 256, 0, stream>>>(PARGS(u16));
    #undef PARGS

    #define ARGS(TT) \
      (const TT*)d_in[0],(const TT*)d_in[1],(const TT*)d_in[2],(const TT*)d_in[4], \
      (const TT*)d_in[5],(const TT*)d_in[6],(const TT*)d_in[7],(const TT*)d_in[8], \
      (const TT*)d_in[12],(const TT*)d_in[10],(const TT*)d_in[20], \
      (const TT*)d_in[16],(const TT*)d_in[14],(const TT*)d_in[18], \
      (const TT*)d_in[22],(const TT*)d_in[24], \
      (TT*)d_out, (TT*)d_out + (size_t)B*32*16, flag, frag
    fused_kernel<float><<<B, 256, 0, stream>>>(ARGS(float));
    fused_kernel<u16><<<B, 256, 0, stream>>>(ARGS(u16));
    #undef ARGS
}

// Round 5
// 153.688 us; speedup vs baseline: 2.3639x; 1.2722x over previous
//
#include <hip/hip_runtime.h>
#include <hip/hip_bf16.h>

typedef unsigned int u32;
typedef unsigned short u16;
typedef __attribute__((ext_vector_type(8))) short short8;
typedef __attribute__((ext_vector_type(4))) float f32x4;

#define DEVI __device__ __forceinline__

DEVI float asf(u32 u){ union{u32 i; float f;} v; v.i=u; return v.f; }
DEVI u16 f2b(float x){ u32 b = __float_as_uint(x); u32 r = b + 0x7fffu + ((b>>16)&1u); return (u16)(r>>16); }
DEVI float b2f(u16 h){ return asf(((u32)h)<<16); }
DEVI float lk(float x){ return x > 0.f ? x : 0.01f*x; }
DEVI short8 lds8(const u16* p){ return *reinterpret_cast<const short8*>(p); }

#define MFMA(a,b,c) __builtin_amdgcn_mfma_f32_16x16x32_bf16((a),(b),(c),0,0,0)

// ---- weight fragment regions in d_ws (u16 elements) ----
// TOTAL = 206848 bytes — MUST stay < 207872 (round-3-proven ws_size floor;
// round 4 at 218112 B overran d_ws and corrupted the harness pristine copy).
// layout consumed as: frag[ (tile*64 + lane)*8 + j ]  with col=lane&15, k=(lane>>4)*8+j
#define FRAG_P4_OFF 36864   // P3: 24nt x 3ks  (s_w|sa_w|sq_w, K 96 zero-padded)
#define FRAG_P8_OFF 86016   // P4: 24nt x 4ks  (q_w|k_w|v_w, K 128)
#define FRAG_P9_OFF 102400  // P8: 4nt x 8ks   (f1_w, K 256)
#define FRAG_TOTAL  103424  // P9: 1nt x 2ks   (f2_w, K 64)
// conv weight fragments (FC1/FC2) are built per-block in LDS — NOT in d_ws.

__global__ void prelude_k(const float* __restrict__ sw, const float* __restrict__ saw,
                          const float* __restrict__ sqw,
                          const float* __restrict__ qw, const float* __restrict__ kw,
                          const float* __restrict__ vw,
                          const float* __restrict__ f1w, const float* __restrict__ f2w,
                          u16* __restrict__ frag)
{
    int idx = blockIdx.x*256 + threadIdx.x;
    if (idx >= FRAG_TOTAL) return;
    if (idx < FRAG_P4_OFF) {
        int j = idx & 7, lane = (idx>>3)&63, r2 = idx>>9;
        int ks = r2 % 3, nt = r2 / 3;
        int fl = lane&15, kg = lane>>4;
        int k = ks*32 + kg*8 + j;
        float w = 0.f;
        if (nt < 8)       { int c = nt*16+fl;      if (k < 66) w = sw[c*66+k]; }
        else if (nt < 16) { int c = (nt-8)*16+fl;  if (k < 82) w = saw[c*82+k]; }
        else              { int c = (nt-16)*16+fl; if (k < 66) w = sqw[c*66+k]; }
        frag[idx] = f2b(w);
    } else if (idx < FRAG_P8_OFF) {
        int e = idx - FRAG_P4_OFF;
        int j = e&7, lane = (e>>3)&63, r2 = e>>9;
        int ks = r2 & 3, nt = r2 >> 2;
        int fl = lane&15, kg = lane>>4;
        int k = ks*32 + kg*8 + j;
        float w;
        if (nt < 8)       w = qw[(nt*16+fl)*128 + k];
        else if (nt < 16) w = kw[((nt-8)*16+fl)*128 + k];
        else              w = vw[((nt-16)*16+fl)*128 + k];
        frag[idx] = f2b(w);
    } else if (idx < FRAG_P9_OFF) {
        int e = idx - FRAG_P8_OFF;
        int j = e&7, lane = (e>>3)&63, r2 = e>>9;
        int ks = r2&7, nt = r2>>3;
        int k = ks*32 + (lane>>4)*8 + j;
        frag[idx] = f2b(f1w[(nt*16+(lane&15))*256 + k]);
    } else {
        int e = idx - FRAG_P9_OFF;
        int j = e&7, lane = (e>>3)&63, r2 = e>>9;   // r2 = ks in {0,1}
        int k = r2*32 + (lane>>4)*8 + j;
        frag[idx] = f2b(f2w[(lane&15)*64 + k]);
    }
}

// ---- LDS map (bytes); row strides odd multiples of 16B for b128 reads ----
#define L_STH 0       // u16 [32][104]  states                 [P0 -> P3]
#define L_SQH 6656    // u16 [32][136]  sq embedding           [P3 -> P8]
#define L_SEH 15360   // u16 [32][136]                         [P3 -> P4]
#define L_SAH 24064   // u16 [32][136]                         [P3 -> P4]
#define L_QH  32768   // u16 [32][136]  queries (pre-scaled)   [P4 -> P5]
#define L_KH  41472   // u16 [32][136]  keys                   [P4 -> P5]
#define L_VT  50176   // u16 [128][40]  values TRANSPOSED      [P4 -> P7]
// aliases (liveness-checked):
#define L_AF   6656   // f32 [2400]     conv input             [P0   -> P05]
#define L_IM   16384  // u16 [288][40]  im2col cols 0..31;     [P05  -> P1]
                      //     FC1 frags in cols 32..39 rows 0..63 [P0 -> P1]
#define L_C1H  39424  // u16 [32][168]  conv1 out (pad@P05)    [P05  -> P2]
#define L_FC2  50176  // u16 [5120]     conv2 w frags          [P0   -> P2] (in Vt slot)
#define L_SCF 0       // f32 [32][36]   scores                 [P5 -> P6]
#define L_W32 41472   // u16 [32][40]   softmax w, zero diag   [P6 -> P7]
#define L_AGG 15360   // u16 [32][136]  agg                    [P7 -> P8]
#define L_H1  24064   // u16 [32][72]   f1 out                 [P8 -> P9]
#define SMEM_BYTES 60416

__global__ __launch_bounds__(512, 2)
void fused_kernel(const float* __restrict__ xs, const float* __restrict__ pos,
                  const float* __restrict__ oh, const float* __restrict__ act,
                  const float* __restrict__ c1w, const float* __restrict__ c1b,
                  const float* __restrict__ c2w, const float* __restrict__ c2b,
                  const float* __restrict__ sb,  const float* __restrict__ sab,
                  const float* __restrict__ sqb,
                  const float* __restrict__ qb,  const float* __restrict__ kb,
                  const float* __restrict__ vb,
                  const float* __restrict__ f1b, const float* __restrict__ f2b_,
                  float* __restrict__ outv, float* __restrict__ outw,
                  const u16* __restrict__ frag)
{
    __shared__ __align__(16) char smem[SMEM_BYTES];

    const int b = blockIdx.x, tid = threadIdx.x;
    const int lane = tid & 63, wv = tid >> 6;
    const int fl = lane & 15, kg = lane >> 4;

    u16* STh = (u16*)(smem + L_STH);
    u16* SQh = (u16*)(smem + L_SQH);
    u16* SEh = (u16*)(smem + L_SEH);
    u16* SAh = (u16*)(smem + L_SAH);
    u16* Qh  = (u16*)(smem + L_QH);
    u16* Kh  = (u16*)(smem + L_KH);
    u16* Vt  = (u16*)(smem + L_VT);
    float* Af  = (float*)(smem + L_AF);
    u16* IM   = (u16*)(smem + L_IM);
    u16* C1h  = (u16*)(smem + L_C1H);
    u16* FC2L = (u16*)(smem + L_FC2);
    float* SCf = (float*)(smem + L_SCF);
    u16* W32h = (u16*)(smem + L_W32);
    u16* AGGh = (u16*)(smem + L_AGG);
    u16* H1h  = (u16*)(smem + L_H1);
    const u16* F3  = frag;
    const u16* F4  = frag + FRAG_P4_OFF;
    const u16* F8  = frag + FRAG_P8_OFF;
    const u16* F9  = frag + FRAG_P9_OFF;

    // ---------------- P0: stage conv input (f32), pose/onehot/actions (bf16),
    //                     conv weight fragments (FC1 -> IM cols 32..39, FC2 -> FC2L) ----------------
    for (int i = tid*2; i < 2400; i += 1024) {
        float2 v = *reinterpret_cast<const float2*>(xs + b*2400 + i);
        Af[i] = v.x; Af[i+1] = v.y;
    }
    for (int i = tid; i < 64; i += 512)   { int n=i>>1, j=i&1;  STh[n*104+32+j] = f2b(pos[(b*32+n)*2+j]); }
    for (int i = tid; i < 1024; i += 512) { int n=i>>5, m=i&31; STh[n*104+34+m] = f2b(oh[(b*32+n)*32+m]); }
    { int n=tid>>4, j=tid&15; STh[n*104+66+j] = f2b(act[(b*32+n)*16+j]); }
    for (int i = tid; i < 704; i += 512)  { int n=i/22, j=i-n*22; STh[n*104+82+j] = 0; }  // zero K-pad
    {   // FC1: conv1 w fragments, lane l elems j at IM[l*40+32+j] (16B-aligned per lane)
        int j = tid & 7, l2 = tid >> 3;   // l2 in 0..63
        int k = (l2 >> 4)*8 + j;
        IM[l2*40 + 32 + j] = f2b((k < 27) ? c1w[(l2 & 15)*27 + k] : 0.f);
    }
    for (int e = tid; e < 5120; e += 512) {  // FC2: conv2 w fragments
        int j = e & 7, l2 = (e >> 3) & 63, r2 = e >> 9;   // r2 = nt*5+ks
        int ks = r2 % 5, nt = r2 / 5;
        int k = ks*32 + (l2 >> 4)*8 + j;
        FC2L[e] = f2b((k < 144) ? c2w[(nt*16 + (l2 & 15))*144 + k] : 0.f);
    }
    __syncthreads();

    // ---------------- P05: im2col (Af -> IM bf16 cols 0..31) + zero C1h K-pad ----------------
    for (int e = tid; e < 9216; e += 512) {
        int row = e >> 5, k = e & 31;
        int n = row / 9, p = row - n*9;
        float v = 0.f;
        if (k < 27) {
            int ic = k / 9, q = k - ic*9;
            int y = p/3 + q/3, x = (p - (p/3)*3) + (q - (q/3)*3);
            v = Af[n*75 + ic*25 + y*5 + x];
        }
        IM[row*40 + k] = f2b(v);
    }
    for (int i = tid; i < 768; i += 512) { int n = i/24, j = i - n*24; C1h[n*168 + 144 + j] = 0; }
    __syncthreads();

    // ---------------- P1: conv1 via MFMA  [288x32]@[32x16] -> C1h[n][oc*9+p] ----------------
    for (int t = wv; t < 18; t += 8) {
        f32x4 acc = {0.f,0.f,0.f,0.f};
        acc = MFMA(lds8(IM + (t*16 + fl)*40 + kg*8), lds8(IM + lane*40 + 32), acc);
        float bv = c1b[fl];
        #pragma unroll
        for (int r = 0; r < 4; ++r) {
            int row = t*16 + kg*4 + r;
            int n = row / 9, p = row - n*9;
            C1h[n*168 + fl*9 + p] = f2b(lk(acc[r] + bv));
        }
    }
    __syncthreads();

    // ---------------- P2: conv2 via MFMA  [32x160]@[160x32] -> STh cols 0..31 ----------------
    if (wv < 4) {
        int mt = wv >> 1, nt = wv & 1;
        f32x4 acc = {0.f,0.f,0.f,0.f};
        const u16* ap = C1h + (mt*16 + fl)*168 + kg*8;
        const u16* bp = FC2L + ((nt*5)*64 + lane)*8;
        #pragma unroll
        for (int ks = 0; ks < 5; ++ks)
            acc = MFMA(lds8(ap + ks*32), lds8(bp + ks*512), acc);
        float bv = c2b[nt*16 + fl];
        #pragma unroll
        for (int r = 0; r < 4; ++r)
            STh[(mt*16 + kg*4 + r)*104 + nt*16 + fl] = f2b(lk(acc[r] + bv));
    }
    __syncthreads();

    // ---------------- P3: [32x96]@[96x384] -> SE|SA|SQ (MFMA, bias+leaky) ----------------
    for (int t = wv; t < 48; t += 8) {
        int nt = t >> 1, mt = t & 1;
        f32x4 acc = {0.f,0.f,0.f,0.f};
        const u16* ap = STh + (mt*16 + fl)*104 + kg*8;
        const u16* bp = F3 + ((nt*3)*64 + lane)*8;
        #pragma unroll
        for (int ks = 0; ks < 3; ++ks)
            acc = MFMA(lds8(ap + ks*32), lds8(bp + ks*512), acc);
        u16* dst; const float* bias; int colOff;
        if (nt < 8)       { dst = SEh; bias = sb;  colOff = nt*16; }
        else if (nt < 16) { dst = SAh; bias = sab; colOff = (nt-8)*16; }
        else              { dst = SQh; bias = sqb; colOff = (nt-16)*16; }
        float bv = bias[colOff + fl];
        int rowb = mt*16 + kg*4;
        #pragma unroll
        for (int r = 0; r < 4; ++r)
            dst[(rowb+r)*136 + colOff + fl] = f2b(lk(acc[r] + bv));
    }
    __syncthreads();

    // ---------------- P4: Q|K|V (MFMA; Q pre-scaled; V transposed) ----------------
    for (int t = wv; t < 48; t += 8) {
        int nt = t >> 1, mt = t & 1;
        const u16* A = (nt < 8) ? SEh : SAh;
        f32x4 acc = {0.f,0.f,0.f,0.f};
        const u16* ap = A + (mt*16 + fl)*136 + kg*8;
        const u16* bp = F4 + ((nt*4)*64 + lane)*8;
        #pragma unroll
        for (int ks = 0; ks < 4; ++ks)
            acc = MFMA(lds8(ap + ks*32), lds8(bp + ks*512), acc);
        int rowb = mt*16 + kg*4;
        if (nt < 8) {
            float bv = qb[nt*16 + fl];
            #pragma unroll
            for (int r = 0; r < 4; ++r)
                Qh[(rowb+r)*136 + nt*16 + fl] = f2b((acc[r] + bv)*0.08838834764831845f);
        } else if (nt < 16) {
            float bv = kb[(nt-8)*16 + fl];
            #pragma unroll
            for (int r = 0; r < 4; ++r)
                Kh[(rowb+r)*136 + (nt-8)*16 + fl] = f2b(acc[r] + bv);
        } else {
            int c = (nt-16)*16 + fl;
            float bv = vb[c];
            #pragma unroll
            for (int r = 0; r < 4; ++r)
                Vt[c*40 + rowb + r] = f2b(acc[r] + bv);
        }
    }
    __syncthreads();

    // ---------------- P5: score = Q @ K^T ----------------
    if (wv < 4) {
        int nt = wv >> 1, mt = wv & 1;
        f32x4 acc = {0.f,0.f,0.f,0.f};
        const u16* ap = Qh + (mt*16 + fl)*136 + kg*8;
        const u16* bp = Kh + (nt*16 + fl)*136 + kg*8;
        #pragma unroll
        for (int ks = 0; ks < 4; ++ks)
            acc = MFMA(lds8(ap + ks*32), lds8(bp + ks*32), acc);
        int rowb = mt*16 + kg*4;
        #pragma unroll
        for (int r = 0; r < 4; ++r)
            SCf[(rowb+r)*36 + nt*16 + fl] = acc[r];
    }
    __syncthreads();

    // ---------------- P6: off-diagonal softmax -> outw + W32 (zero diag) ----------------
    {
        int n = tid >> 4, g = tid & 15;
        int m0 = (g < n) ? g : g+1;
        int j1 = g + 16;
        bool v1 = j1 < 31;
        int m1 = (j1 < n) ? j1 : j1+1;
        float e0 = SCf[n*36 + m0];
        float e1 = v1 ? SCf[n*36 + m1] : -1e30f;
        float mx = fmaxf(e0, e1);
        #pragma unroll
        for (int d = 8; d; d >>= 1) mx = fmaxf(mx, __shfl_xor(mx, d, 16));
        float x0 = __expf(e0 - mx);
        float x1 = v1 ? __expf(e1 - mx) : 0.f;
        float s = x0 + x1;
        #pragma unroll
        for (int d = 8; d; d >>= 1) s += __shfl_xor(s, d, 16);
        float inv = 1.f/s;
        float w0 = x0*inv, w1 = x1*inv;
        W32h[n*40 + m0] = f2b(w0);
        if (v1) W32h[n*40 + m1] = f2b(w1);
        if (g == 0) W32h[n*40 + n] = 0;
        float* wp = outw + (b*32 + n)*31;
        wp[g] = w0;
        if (v1) wp[j1] = w1;
    }
    __syncthreads();

    // ---------------- P7: agg = W32 @ V  (B from Vt) ----------------
    for (int t = wv; t < 16; t += 8) {
        int nt = t >> 1, mt = t & 1;
        f32x4 acc = {0.f,0.f,0.f,0.f};
        acc = MFMA(lds8(W32h + (mt*16 + fl)*40 + kg*8),
                   lds8(Vt + (nt*16 + fl)*40 + kg*8), acc);
        int rowb = mt*16 + kg*4;
        #pragma unroll
        for (int r = 0; r < 4; ++r)
            AGGh[(rowb+r)*136 + nt*16 + fl] = f2b(acc[r]);
    }
    __syncthreads();

    // ---------------- P8: f1 ([32x256]@[256x64], K split sq|agg, bias+leaky) ----------------
    {
        int t = wv;
        int nt = t >> 1, mt = t & 1;
        f32x4 acc = {0.f,0.f,0.f,0.f};
        const u16* bp = F8 + ((nt*8)*64 + lane)*8;
        #pragma unroll
        for (int ks = 0; ks < 8; ++ks) {
            const u16* ap = ((ks < 4) ? SQh : AGGh) + (mt*16 + fl)*136 + (ks&3)*32 + kg*8;
            acc = MFMA(lds8(ap), lds8(bp + ks*512), acc);
        }
        float bv = f1b[nt*16 + fl];
        int rowb = mt*16 + kg*4;
        #pragma unroll
        for (int r = 0; r < 4; ++r)
            H1h[(rowb+r)*72 + nt*16 + fl] = f2b(lk(acc[r] + bv));
    }
    __syncthreads();

    // ---------------- P9: f2 ([32x64]@[64x16]) -> value out ----------------
    if (wv < 2) {
        int mt = wv;
        f32x4 acc = {0.f,0.f,0.f,0.f};
        const u16* ap = H1h + (mt*16 + fl)*72 + kg*8;
        const u16* bp = F9 + lane*8;
        #pragma unroll
        for (int ks = 0; ks < 2; ++ks)
            acc = MFMA(lds8(ap + ks*32), lds8(bp + ks*512), acc);
        float bv = f2b_[fl];
        int rowb = mt*16 + kg*4;
        #pragma unroll
        for (int r = 0; r < 4; ++r)
            outv[(b*32 + rowb + r)*16 + fl] = acc[r] + bv;
    }
}

extern "C" void kernel_launch(void* const* d_in, const int* in_sizes, int n_in,
                              void* d_out, int out_size, void* d_ws, size_t ws_size,
                              hipStream_t stream) {
    const int B = in_sizes[0] / (32*75);
    u16* frag = (u16*)d_ws;

    // indices: 0 xs,1 pos,2 oh,3 policies,4 act, 5 c1w,6 c1b,7 c2w,8 c2b,
    // 9 sa_w,10 sa_b,11 s_w,12 s_b, 13 k_w,14 k_b, 15 q_w,16 q_b, 17 v_w,18 v_b,
    // 19 sq_w,20 sq_b, 21 f1_w,22 f1_b, 23 f2_w,24 f2_b
    const int PRE_GRID = (FRAG_TOTAL + 255)/256;
    prelude_k<<<PRE_GRID, 256, 0, stream>>>(
        (const float*)d_in[11], (const float*)d_in[9],  (const float*)d_in[19],
        (const float*)d_in[15], (const float*)d_in[13], (const float*)d_in[17],
        (const float*)d_in[21], (const float*)d_in[23], frag);

    fused_kernel<<<B, 512, 0, stream>>>(
        (const float*)d_in[0],  (const float*)d_in[1],  (const float*)d_in[2],
        (const float*)d_in[4],
        (const float*)d_in[5],  (const float*)d_in[6],
        (const float*)d_in[7],  (const float*)d_in[8],
        (const float*)d_in[12], (const float*)d_in[10], (const float*)d_in[20],
        (const float*)d_in[16], (const float*)d_in[14], (const float*)d_in[18],
        (const float*)d_in[22], (const float*)d_in[24],
        (float*)d_out, (float*)d_out + (size_t)B*32*16, frag);
}